// Round 1
// baseline (3208.283 us; speedup 1.0000x reference)
//
#include <hip/hip_runtime.h>
#include <math.h>

#define EMB 1024
#define NH 64
#define TSEQ 4096
#define NB 4
#define NROWS (NB * TSEQ)

constexpr float kScale = 1.0f / 1048576.0f;       // 1 / C^2, C = 1024
constexpr float kLog2e = 1.44269504088896f;

// ---------------------------------------------------------------------------
// Kernel 1: fused projection  k = x@Wk, qT = (x@Wq)^T (per batch), v = x@Wv
// Block = 256 threads (4 waves), 32 rows per block. x staged in LDS in
// 128-wide e-chunks; each wave register-blocks 8 rows x 3 weights so W
// streams once per block (shared across waves via L1).
// ---------------------------------------------------------------------------
__global__ __launch_bounds__(256) void proj_kernel(
    const float* __restrict__ x, const float* __restrict__ Wk,
    const float* __restrict__ Wq, const float* __restrict__ Wv,
    float* __restrict__ K, float* __restrict__ Qt, float* __restrict__ V) {
  __shared__ float xs[32][128];
  const int tid = threadIdx.x;
  const int lane = tid & 63;
  const int wv = tid >> 6;          // wave id 0..3
  const int r0 = blockIdx.x * 32;   // first row of this block

  float acc[8][3];
#pragma unroll
  for (int i = 0; i < 8; ++i)
#pragma unroll
    for (int j = 0; j < 3; ++j) acc[i][j] = 0.f;

  for (int e0 = 0; e0 < EMB; e0 += 128) {
    __syncthreads();  // previous chunk's reads done
    // stage x[r0:r0+32, e0:e0+128) -> xs (1024 float4, 4 per thread)
#pragma unroll
    for (int it = 0; it < 4; ++it) {
      int f4 = tid + 256 * it;          // 0..1023
      int row = f4 >> 5, e4 = f4 & 31;  // 32 float4 per row
      float4 val = *reinterpret_cast<const float4*>(
          x + (size_t)(r0 + row) * EMB + e0 + e4 * 4);
      *reinterpret_cast<float4*>(&xs[row][e4 * 4]) = val;
    }
    __syncthreads();

    const int rb = wv * 8;  // this wave's row sub-block
    for (int el = 0; el < 128; el += 4) {
      float4 xv[8];
#pragma unroll
      for (int rr = 0; rr < 8; ++rr)
        xv[rr] = *reinterpret_cast<const float4*>(&xs[rb + rr][el]);
#pragma unroll
      for (int u = 0; u < 4; ++u) {
        int e = e0 + el + u;
        float wk = Wk[e * NH + lane];   // coalesced across lanes; L1-shared
        float wq = Wq[e * NH + lane];
        float wvv = Wv[e * NH + lane];
#pragma unroll
        for (int rr = 0; rr < 8; ++rr) {
          float xe = (u == 0)   ? xv[rr].x
                     : (u == 1) ? xv[rr].y
                     : (u == 2) ? xv[rr].z
                                : xv[rr].w;
          acc[rr][0] = fmaf(xe, wk, acc[rr][0]);
          acc[rr][1] = fmaf(xe, wq, acc[rr][1]);
          acc[rr][2] = fmaf(xe, wvv, acc[rr][2]);
        }
      }
    }
  }

#pragma unroll
  for (int rr = 0; rr < 8; ++rr) {
    int r = r0 + wv * 8 + rr;
    int b = r >> 12, t = r & (TSEQ - 1);
    K[(size_t)r * NH + lane] = acc[rr][0];
    // q stored transposed per batch: qT[b][h][t] -> coalesced reads in attn
    Qt[((size_t)b * NH + lane) * TSEQ + t] = acc[rr][1];
    V[(size_t)r * NH + lane] = acc[rr][2];
  }
}

// ---------------------------------------------------------------------------
// Kernel 2: causal flash attention, fp32.
// weight(i,j) = k_i . q_j * 2^-20 (k plays the query role per reference).
// One wave = 2 consecutive query rows (k rows cached in 128 VGPRs).
// Score phase: lane = j within 64-wide tile, reads qT coalesced.
// PV phase:    lane = h, p broadcast via readlane-style shuffles.
// ---------------------------------------------------------------------------
__global__ __launch_bounds__(256) void attn_kernel(
    const float* __restrict__ K, const float* __restrict__ Qt,
    const float* __restrict__ V, float* __restrict__ out) {
  const int tid = threadIdx.x;
  const int lane = tid & 63;
  const int wv = tid >> 6;
  const int gw = blockIdx.x * 4 + wv;  // 0..8191
  const int rA = gw * 2;               // global row pair
  const int b = rA >> 12;
  const int iA = rA & (TSEQ - 1);
  const int iB = iA + 1;

  const float* kb = K + (size_t)b * TSEQ * NH;
  const float* qb = Qt + (size_t)b * NH * TSEQ;
  const float* vb = V + (size_t)b * TSEQ * NH;

  // cache both k rows in registers (uniform loads -> broadcast)
  float ka[64], kc[64];
#pragma unroll
  for (int h = 0; h < 64; ++h) {
    ka[h] = kb[(size_t)iA * NH + h];
    kc[h] = kb[(size_t)iB * NH + h];
  }

  float mA = -INFINITY, mB = -INFINITY;
  float lA = 0.f, lB = 0.f;
  float accA = 0.f, accB = 0.f;

  const int ntile = (iB >> 6) + 1;
  for (int jt = 0; jt < ntile; ++jt) {
    const int j0 = jt * 64;
    const int j = j0 + lane;

    // ---- scores: s = k_i . q_j ----
    float sA = 0.f, sB = 0.f;
#pragma unroll
    for (int h = 0; h < 64; ++h) {
      float qv = qb[(size_t)h * TSEQ + j];  // coalesced across lanes
      sA = fmaf(ka[h], qv, sA);
      sB = fmaf(kc[h], qv, sB);
    }
    sA = (j <= iA) ? sA * kScale : -INFINITY;
    sB = (j <= iB) ? sB * kScale : -INFINITY;

    // ---- online softmax ----
    float mtA = sA, mtB = sB;
#pragma unroll
    for (int off = 32; off >= 1; off >>= 1) {
      mtA = fmaxf(mtA, __shfl_xor(mtA, off));
      mtB = fmaxf(mtB, __shfl_xor(mtB, off));
    }
    float mnA = fmaxf(mA, mtA), mnB = fmaxf(mB, mtB);
    float pA = __builtin_amdgcn_exp2f((sA - mnA) * kLog2e);
    float pB = __builtin_amdgcn_exp2f((sB - mnB) * kLog2e);
    float cA = __builtin_amdgcn_exp2f((mA - mnA) * kLog2e);
    float cB = __builtin_amdgcn_exp2f((mB - mnB) * kLog2e);
    mA = mnA;
    mB = mnB;
    float tA = pA, tB = pB;
#pragma unroll
    for (int off = 32; off >= 1; off >>= 1) {
      tA += __shfl_xor(tA, off);
      tB += __shfl_xor(tB, off);
    }
    lA = lA * cA + tA;
    lB = lB * cB + tB;
    accA *= cA;
    accB *= cB;

    // ---- PV: lane = h, p_j broadcast from lane jj (compile-time index) ----
#pragma unroll
    for (int jj = 0; jj < 64; ++jj) {
      float vv = vb[(size_t)(j0 + jj) * NH + lane];  // coalesced
      accA = fmaf(__shfl(pA, jj), vv, accA);
      accB = fmaf(__shfl(pB, jj), vv, accB);
    }
  }

  out[((size_t)b * TSEQ + iA) * NH + lane] = accA / lA;
  out[((size_t)b * TSEQ + iB) * NH + lane] = accB / lB;
}

// ---------------------------------------------------------------------------
extern "C" void kernel_launch(void* const* d_in, const int* in_sizes, int n_in,
                              void* d_out, int out_size, void* d_ws,
                              size_t ws_size, hipStream_t stream) {
  const float* x = (const float*)d_in[0];
  const float* Wk = (const float*)d_in[1];
  const float* Wq = (const float*)d_in[2];
  const float* Wv = (const float*)d_in[3];
  float* out = (float*)d_out;

  float* K = (float*)d_ws;                       // [B,T,64]   4 MB
  float* Qt = K + (size_t)NROWS * NH;            // [B,64,T]   4 MB
  float* V = Qt + (size_t)NROWS * NH;            // [B,T,64]   4 MB

  proj_kernel<<<NROWS / 32, 256, 0, stream>>>(x, Wk, Wq, Wv, K, Qt, V);
  attn_kernel<<<NROWS / 8, 256, 0, stream>>>(K, Qt, V, out);
}

// Round 2
// 130.791 us; speedup vs baseline: 24.5299x; 24.5299x over previous
//
#include <hip/hip_runtime.h>
#include <math.h>

#define EMB 1024
#define NH 64
#define TSEQ 4096
#define NB 4
#define NROWS (NB * TSEQ)

typedef __bf16 bf16;
typedef __bf16 bf16x8 __attribute__((ext_vector_type(8)));
typedef float f32x4 __attribute__((ext_vector_type(4)));

constexpr float kScale = 1.0f / 1048576.0f;  // 1/C^2
constexpr float kL2E = 1.44269504088896f;

__device__ __forceinline__ f32x4 mfma16(bf16x8 a, bf16x8 b, f32x4 c) {
  return __builtin_amdgcn_mfma_f32_16x16x32_bf16(a, b, c, 0, 0, 0);
}

// ---------------------------------------------------------------------------
// prep: Wt[mat][h][e] = bf16(W[mat][e][h])   (3 x 64 x 1024)
// ---------------------------------------------------------------------------
__global__ void prep_w(const float* __restrict__ Wk, const float* __restrict__ Wq,
                       const float* __restrict__ Wv, bf16* __restrict__ Wt) {
  const int blk = blockIdx.x;  // mat*64 + h
  const int mat = blk >> 6, h = blk & 63;
  const float* W = (mat == 0) ? Wk : (mat == 1 ? Wq : Wv);
  const int e0 = threadIdx.x * 4;
  bf16* dst = Wt + ((size_t)blk << 10) + e0;
#pragma unroll
  for (int u = 0; u < 4; ++u) dst[u] = (bf16)W[(e0 + u) * NH + h];
}

// ---------------------------------------------------------------------------
// proj: K/Q row-major bf16 [16384][64], V transposed bf16 Vt[b*64+h][4096].
// One wave = 16 rows x all 192 output cols (12 N-subtiles). A-frag converted
// from fp32 x on the fly; B-frags are 16B contiguous reads from Wt.
// ---------------------------------------------------------------------------
__global__ __launch_bounds__(256) void proj_mfma(
    const float* __restrict__ x, const bf16* __restrict__ Wt,
    bf16* __restrict__ Kb, bf16* __restrict__ Qb, bf16* __restrict__ Vt) {
  const int tid = threadIdx.x, lane = tid & 63, wid = tid >> 6;
  const int rb = blockIdx.x * 64 + wid * 16;
  const int lr = lane & 15, lg = lane >> 4;

  f32x4 acc[12];
#pragma unroll
  for (int i = 0; i < 12; ++i) acc[i] = (f32x4){0.f, 0.f, 0.f, 0.f};

  const float* xrow = x + (size_t)(rb + lr) * EMB + lg * 8;
  for (int ks = 0; ks < 32; ++ks) {
    const int e0 = ks * 32;
    float4 xa = *(const float4*)(xrow + e0);
    float4 xb = *(const float4*)(xrow + e0 + 4);
    bf16x8 af;
    af[0] = (bf16)xa.x; af[1] = (bf16)xa.y; af[2] = (bf16)xa.z; af[3] = (bf16)xa.w;
    af[4] = (bf16)xb.x; af[5] = (bf16)xb.y; af[6] = (bf16)xb.z; af[7] = (bf16)xb.w;
#pragma unroll
    for (int sub = 0; sub < 12; ++sub) {
      // Wt row = mat*64 + hs*16 + lr = sub*16 + lr
      bf16x8 bfr = *(const bf16x8*)(Wt + (((size_t)(sub * 16 + lr)) << 10) + e0 + lg * 8);
      acc[sub] = mfma16(af, bfr, acc[sub]);
    }
  }
#pragma unroll
  for (int sub = 0; sub < 12; ++sub) {
    const int mat = sub >> 2, hs = sub & 3;
#pragma unroll
    for (int r = 0; r < 4; ++r) {
      const int row = rb + lg * 4 + r;
      const int h = hs * 16 + lr;
      bf16 v = (bf16)acc[sub][r];
      if (mat == 0) {
        Kb[(size_t)row * NH + h] = v;
      } else if (mat == 1) {
        Qb[(size_t)row * NH + h] = v;
      } else {
        const int b = row >> 12, t = row & (TSEQ - 1);
        Vt[((size_t)(b * NH + h)) * TSEQ + t] = v;
      }
    }
  }
}

// ---------------------------------------------------------------------------
// attn: flash attention, bf16 MFMA. Wave = one 16-row i-tile, one j-parity.
// Block: waves {0,1} -> i-tile g (parity 0/1), waves {2,3} -> i-tile 255-g.
// S = K_i · Q_j^T (16x64 per j-tile, 8 mfma), online softmax in D-layout,
// P transposed through swizzled LDS, PV = P · V (8 mfma). Parity merge at end.
// ---------------------------------------------------------------------------
__global__ __launch_bounds__(256) void attn_mfma(
    const bf16* __restrict__ Kb, const bf16* __restrict__ Qb,
    const bf16* __restrict__ Vt, float* __restrict__ out) {
  __shared__ char pbuf[4 * 2048];
  __shared__ float mbuf[2][64][26];

  const int tid = threadIdx.x, lane = tid & 63, wid = tid >> 6;
  const int lr = lane & 15, lg = lane >> 4;
  const int bx = blockIdx.x;
  const int batch = bx >> 7, g = bx & 127;
  const int it = (wid < 2) ? g : (255 - g);
  const int parity = wid & 1;
  const int ibase = it << 4;
  const int nt = (it >> 2) + 1;

  const bf16* Kp = Kb + ((size_t)batch << 12) * NH;
  const bf16* Qp = Qb + ((size_t)batch << 12) * NH;
  const bf16* Vp = Vt + ((size_t)batch * NH) * TSEQ;
  char* myP = pbuf + wid * 2048;

  const bf16* krow = Kp + (size_t)(ibase + lr) * NH + lg * 8;
  bf16x8 ka0 = *(const bf16x8*)(krow);
  bf16x8 ka1 = *(const bf16x8*)(krow + 32);

  f32x4 acc[4];
  float m_[4], l_[4];
#pragma unroll
  for (int f = 0; f < 4; ++f) acc[f] = (f32x4){0.f, 0.f, 0.f, 0.f};
#pragma unroll
  for (int r = 0; r < 4; ++r) { m_[r] = -INFINITY; l_[r] = 0.f; }

  for (int jt = parity; jt < nt; jt += 2) {
    const int j0 = jt << 6;
    // Q B-frags (8) and V B-frags (8): 16B contiguous per lane
    bf16x8 qf[4][2], vf[4][2];
#pragma unroll
    for (int js = 0; js < 4; ++js) {
      const bf16* qrow = Qp + (size_t)(j0 + js * 16 + lr) * NH + lg * 8;
      qf[js][0] = *(const bf16x8*)qrow;
      qf[js][1] = *(const bf16x8*)(qrow + 32);
    }
#pragma unroll
    for (int f = 0; f < 4; ++f) {
      const bf16* vrow = Vp + (size_t)(f * 16 + lr) * TSEQ + j0 + lg * 8;
      vf[f][0] = *(const bf16x8*)vrow;
      vf[f][1] = *(const bf16x8*)(vrow + 32);
    }
    // S = K·Q^T
    f32x4 s[4];
#pragma unroll
    for (int js = 0; js < 4; ++js) {
      s[js] = mfma16(ka0, qf[js][0], (f32x4){0.f, 0.f, 0.f, 0.f});
      s[js] = mfma16(ka1, qf[js][1], s[js]);
    }
    const bool maskT = (jt == nt - 1);
    float p[4][4];
#pragma unroll
    for (int js = 0; js < 4; ++js)
#pragma unroll
      for (int r = 0; r < 4; ++r) {
        float v = s[js][r] * kScale;
        if (maskT) {
          const int i = ibase + lg * 4 + r;
          const int j = j0 + js * 16 + lr;
          if (j > i) v = -INFINITY;
        }
        p[js][r] = v;
      }
    // online softmax (row i lives in 16-lane group; reduce over lane&15)
#pragma unroll
    for (int r = 0; r < 4; ++r) {
      float pm = fmaxf(fmaxf(p[0][r], p[1][r]), fmaxf(p[2][r], p[3][r]));
      pm = fmaxf(pm, __shfl_xor(pm, 1));
      pm = fmaxf(pm, __shfl_xor(pm, 2));
      pm = fmaxf(pm, __shfl_xor(pm, 4));
      pm = fmaxf(pm, __shfl_xor(pm, 8));
      const float mn = fmaxf(m_[r], pm);
      const float c = __builtin_amdgcn_exp2f((m_[r] - mn) * kL2E);
      m_[r] = mn;
      float ts = 0.f;
#pragma unroll
      for (int js = 0; js < 4; ++js) {
        const float pe = __builtin_amdgcn_exp2f((p[js][r] - mn) * kL2E);
        p[js][r] = pe;
        ts += pe;
      }
      ts += __shfl_xor(ts, 1);
      ts += __shfl_xor(ts, 2);
      ts += __shfl_xor(ts, 4);
      ts += __shfl_xor(ts, 8);
      l_[r] = l_[r] * c + ts;
#pragma unroll
      for (int f = 0; f < 4; ++f) acc[f][r] *= c;
    }
    // P -> LDS (bf16, XOR-swizzled rows: 128B-stride rows need ^((i&7)<<4))
#pragma unroll
    for (int js = 0; js < 4; ++js)
#pragma unroll
      for (int r = 0; r < 4; ++r) {
        const int i = lg * 4 + r;
        const int j = js * 16 + lr;
        const int off = ((i << 7) + (j << 1)) ^ ((i & 7) << 4);
        *(bf16*)(myP + off) = (bf16)p[js][r];
      }
    // PV A-frags from LDS (transposed view of P)
    const int roff0 = ((lr << 7) | (lg << 4)) ^ ((lr & 7) << 4);
    const int roff1 = ((lr << 7) | 64 | (lg << 4)) ^ ((lr & 7) << 4);
    bf16x8 pa0 = *(const bf16x8*)(myP + roff0);
    bf16x8 pa1 = *(const bf16x8*)(myP + roff1);
#pragma unroll
    for (int f = 0; f < 4; ++f) {
      acc[f] = mfma16(pa0, vf[f][0], acc[f]);
      acc[f] = mfma16(pa1, vf[f][1], acc[f]);
    }
  }

  // merge parity-1 state into parity-0 wave
  if (parity == 1) {
    const int slot = wid >> 1;
    float* mb = &mbuf[slot][lane][0];
#pragma unroll
    for (int r = 0; r < 4; ++r) { mb[r] = m_[r]; mb[4 + r] = l_[r]; }
#pragma unroll
    for (int f = 0; f < 4; ++f)
#pragma unroll
      for (int r = 0; r < 4; ++r) mb[8 + f * 4 + r] = acc[f][r];
  }
  __syncthreads();
  if (parity == 0) {
    const int slot = wid >> 1;
    const float* mb = &mbuf[slot][lane][0];
#pragma unroll
    for (int r = 0; r < 4; ++r) {
      const float m2 = mb[r], l2 = mb[4 + r];
      const float mm = fmaxf(m_[r], m2);
      const float a1 = __builtin_amdgcn_exp2f((m_[r] - mm) * kL2E);
      const float a2 = (l2 > 0.f) ? __builtin_amdgcn_exp2f((m2 - mm) * kL2E) : 0.f;
      const float inv = 1.f / (l_[r] * a1 + l2 * a2);
      const int row = (batch << 12) + ibase + lg * 4 + r;
#pragma unroll
      for (int f = 0; f < 4; ++f) {
        const float o = (acc[f][r] * a1 + mb[8 + f * 4 + r] * a2) * inv;
        out[(size_t)row * NH + f * 16 + lr] = o;
      }
    }
  }
}

// ---------------------------------------------------------------------------
extern "C" void kernel_launch(void* const* d_in, const int* in_sizes, int n_in,
                              void* d_out, int out_size, void* d_ws,
                              size_t ws_size, hipStream_t stream) {
  const float* x = (const float*)d_in[0];
  const float* Wk = (const float*)d_in[1];
  const float* Wq = (const float*)d_in[2];
  const float* Wv = (const float*)d_in[3];
  float* out = (float*)d_out;

  char* ws = (char*)d_ws;
  bf16* Kb = (bf16*)ws;                          // 2 MB
  bf16* Qb = (bf16*)(ws + (2ull << 20));         // 2 MB
  bf16* Vt = (bf16*)(ws + (4ull << 20));         // 2 MB
  bf16* Wt = (bf16*)(ws + (6ull << 20));         // 384 KB

  prep_w<<<192, 256, 0, stream>>>(Wk, Wq, Wv, Wt);
  proj_mfma<<<256, 256, 0, stream>>>(x, Wt, Kb, Qb, Vt);
  attn_mfma<<<512, 256, 0, stream>>>(Kb, Qb, Vt, out);
}